// Round 1
// 1506.725 us; speedup vs baseline: 1.1477x; 1.1477x over previous
//
#include <hip/hip_runtime.h>
#include <hip/hip_bf16.h>

#define B_   32
#define S_   200
#define H_   512
#define ED_  256
#define NF_  19
#define NROW (B_*S_)      // 6400
#define G4H  (4*H_)       // 2048
#define KIN  (ED_+NF_)    // 275
#define KP_  288          // padded K for input GEMM
#define ALD  296          // A-tile LDS row stride (bf16)

typedef __attribute__((ext_vector_type(8))) short short8;
typedef __attribute__((ext_vector_type(4))) float f32x4;
typedef __attribute__((ext_vector_type(4))) unsigned int u32x4;

// ---------------- workspace layout (bytes) ----------------
#define OFF_G0   0ull
#define SZ_G0    ((size_t)NROW*G4H*4)            // 52428800
#define OFF_LSTM (OFF_G0 + SZ_G0)
#define SZ_LSTM  ((size_t)NROW*H_*4)             // 13107200
#define OFF_CT   (OFF_LSTM + SZ_LSTM)
#define SZ_CT    ((size_t)NROW*NF_*4)            // 486400
#define OFF_CN   (OFF_CT + SZ_CT)
#define OFF_H0   (OFF_CN + SZ_CT)
#define SZ_HB    ((size_t)2*B_*H_*2)             // 65536 (bf16 double buffer)
#define OFF_H1   (OFF_H0 + SZ_HB)
#define OFF_SYNC (OFF_H1 + SZ_HB)                // [1],[2]=accum f32; bytes 64..127 = flags[64]
#define OFF_WB   (OFF_SYNC + 256)                // Wih0 pre-converted bf16 [2048][288]
#define SZ_WB    ((size_t)G4H*KP_*2)             // 1179648

__device__ __forceinline__ unsigned short f2bf(float f) {
    unsigned u = __float_as_uint(f);
    unsigned r = u + 0x7fffu + ((u >> 16) & 1u);
    return (unsigned short)(r >> 16);
}
__device__ __forceinline__ float sigf(float x) { return 1.0f / (1.0f + __expf(-x)); }

// coherent (agent-scope) 16B load, bypasses L1/L2, served at the MALL
#define CLD16(d, p, o) \
    asm volatile("global_load_dwordx4 %0, %1, off offset:" o " sc0 sc1" \
                 : "=v"(d) : "v"(p))
// one fragment plane (16 chunks x 1KB), fully coalesced: lane*16B + j*1024B
#define CLDPLANE(F, b) do { \
    const unsigned short* _pa = (b) + 2048; \
    const unsigned short* _pb = (b) + 6144; \
    CLD16(F[0],_pa,"-4096"); CLD16(F[1],_pa,"-3072"); CLD16(F[2],_pa,"-2048"); CLD16(F[3],_pa,"-1024"); \
    CLD16(F[4],_pa,"0");     CLD16(F[5],_pa,"1024");  CLD16(F[6],_pa,"2048");  CLD16(F[7],_pa,"3072");  \
    CLD16(F[8],_pb,"-4096"); CLD16(F[9],_pb,"-3072"); CLD16(F[10],_pb,"-2048");CLD16(F[11],_pb,"-1024");\
    CLD16(F[12],_pb,"0");    CLD16(F[13],_pb,"1024"); CLD16(F[14],_pb,"2048"); CLD16(F[15],_pb,"3072"); \
} while (0)
// coherent 16B store
#define CST128(a, v) \
    asm volatile("global_store_dwordx4 %0, %1, off sc0 sc1" :: "v"(a), "v"(v) : "memory")
// coherent byte store (flag)
#define CSTB(a, v) \
    asm volatile("global_store_byte %0, %1, off sc0 sc1" :: "v"(a), "v"(v) : "memory")
// plain (cached) 4B load, issue point pinned by asm volatile ordering
#define PLD32(d, p, o) \
    asm volatile("global_load_dword %0, %1, off offset:" o : "=v"(d) : "v"(p))

// fragment-major bf16 index within one parity buffer (16384 elems):
// idx(b,u) = (b>>4)*8192 + (u>>5)*512 + (((u>>3)&3)*16 + (b&15))*8 + (u&7)
// so that consumer lane l, chunk j reads exactly its 16x16x32 A-fragment
// contiguously at plane(mt) + j*512 + l*8.

// ---------------- prep: c_t/c_next, h-buffer init (fragment-major), flag zero ----------------
__global__ __launch_bounds__(256) void prep_kernel(
    const float* __restrict__ C, const float* __restrict__ rep,
    const float* __restrict__ past, const float* __restrict__ seq,
    const float* __restrict__ init_h,
    float* __restrict__ ct, float* __restrict__ cn,
    unsigned short* __restrict__ h0buf, unsigned short* __restrict__ h1buf,
    unsigned* __restrict__ syncbuf)
{
    int idx = blockIdx.x * 256 + threadIdx.x;
    if (idx < NROW * NF_) {
        int m = idx % NF_; int row = idx / NF_;
        int b = row / S_, s = row % S_;
        float cc = C[idx];
        float v0, v1;
        if (m < 7)       { v0 = rep [(b*(S_+1)+s)*7 + m];      v1 = rep [(b*(S_+1)+s+1)*7 + m]; }
        else if (m < 13) { v0 = seq [(b*(S_+1)+s)*6 + (m-7)];  v1 = seq [(b*(S_+1)+s+1)*6 + (m-7)]; }
        else             { v0 = past[(b*(S_+1)+s)*6 + (m-13)]; v1 = past[(b*(S_+1)+s+1)*6 + (m-13)]; }
        ct[idx] = cc * v0;
        cn[idx] = cc * v1;
    }
    int j = idx - NROW * NF_;
    if (j >= 0 && j < B_ * H_) {
        int b = j >> 9, u = j & (H_ - 1);
        int fi = ((b >> 4) * 8192) + ((u >> 5) * 512)
               + ((((u >> 3) & 3) * 16 + (b & 15)) * 8) + (u & 7);
        h0buf[fi] = f2bf(init_h[j]);
        h1buf[fi] = f2bf(init_h[B_ * H_ + j]);
    }
    if (j >= B_ * H_ && j < B_ * H_ + 32) syncbuf[j - B_ * H_] = 0u;
}

// ---------------- prep_w: Wih0 f32[2048][275] -> bf16[2048][288] (zero-pad) ----------------
__global__ __launch_bounds__(256) void prepw_kernel(
    const float* __restrict__ Wih0, unsigned short* __restrict__ wb)
{
    int idx = blockIdx.x * 256 + threadIdx.x;
    if (idx >= G4H * KP_) return;
    int k = idx % KP_; int r = idx / KP_;
    wb[idx] = (k < KIN) ? f2bf(Wih0[(size_t)r * KIN + k]) : (unsigned short)0;
}

// ---------------- G0 = [emb|c_t] @ Wih0^T + bih0 + bhh0  (bf16 MFMA) ----------------
__global__ __launch_bounds__(256) void g0_kernel(
    const int* __restrict__ x_data, const float* __restrict__ embed,
    const unsigned short* __restrict__ wb,
    const float* __restrict__ bih0, const float* __restrict__ bhh0,
    const float* __restrict__ ct, float* __restrict__ G0)
{
    __shared__ unsigned short A[32 * ALD];
    int tid = threadIdx.x;
    int bx = blockIdx.x;
    int mb = bx >> 5;          // 0..199  (row tile of 32)
    int nb = bx & 31;          // 0..31   (col tile of 64)
    int rbase = mb * 32;
    {   // stage A: 32 gathered rows of [emb(256)|c_t(19)|pad]
        int r = tid >> 3, c8 = tid & 7;
        int grow = rbase + r;
        const float* erow = embed + (size_t)x_data[grow] * ED_;
        #pragma unroll
        for (int jj = 0; jj < 8; jj++) {
            float4 v = *(const float4*)(erow + c8 * 32 + jj * 4);
            unsigned short* d = &A[r * ALD + c8 * 32 + jj * 4];
            d[0] = f2bf(v.x); d[1] = f2bf(v.y); d[2] = f2bf(v.z); d[3] = f2bf(v.w);
        }
        if (c8 == 0) {
            const float* crow = ct + (size_t)grow * NF_;
            for (int m = 0; m < NF_; m++) A[r * ALD + ED_ + m] = f2bf(crow[m]);
            for (int m = NF_; m < 32; m++) A[r * ALD + ED_ + m] = 0;
        }
    }
    __syncthreads();
    int lane = tid & 63, w = tid >> 6;
    int ncol = nb * 64 + w * 16 + (lane & 15);   // global gate row
    int kb = (lane >> 4) * 8;
    f32x4 acc0 = {0.f,0.f,0.f,0.f}, acc1 = {0.f,0.f,0.f,0.f};
    #pragma unroll
    for (int ks = 0; ks < 9; ks++) {
        int k0 = ks * 32 + kb;
        short8 bfr = *(const short8*)(wb + (size_t)ncol * KP_ + k0);
        short8 a0 = *(const short8*)&A[(lane & 15) * ALD + k0];
        short8 a1 = *(const short8*)&A[(16 + (lane & 15)) * ALD + k0];
        acc0 = __builtin_amdgcn_mfma_f32_16x16x32_bf16(a0, bfr, acc0, 0, 0, 0);
        acc1 = __builtin_amdgcn_mfma_f32_16x16x32_bf16(a1, bfr, acc1, 0, 0, 0);
    }
    float bias = bih0[ncol] + bhh0[ncol];
    #pragma unroll
    for (int r = 0; r < 4; r++) {
        int row0 = (lane >> 4) * 4 + r;
        G0[(size_t)(rbase + row0) * G4H + ncol]      = acc0[r] + bias;
        G0[(size_t)(rbase + 16 + row0) * G4H + ncol] = acc1[r] + bias;
    }
}

// ---------------- persistent 2-layer LSTM scan ----------------
// 64 blocks x 256 threads. Block p owns units [8p, 8p+8) of each layer.
// Weights stationary in VGPRs. h exchanged through global bf16 double buffers
// stored in MFMA FRAGMENT-MAJOR layout -> consumer loads are fully coalesced
// (lane*16B contiguous, 1KB per instruction). Producer packs 8 units into one
// dwordx4 coherent store via 4 shuffles.
// Grid sync: per-block byte flag (= step count, monotonic) + single-load
// 64-flag wave poll; no atomic RMW chain, no tid0 release funnel.
// G0 gate rows are prefetched (pinned asm loads) BEFORE the flag wait so HBM
// latency overlaps the barrier round trip.
__global__ __launch_bounds__(256, 1) void scan_kernel(
    const float* __restrict__ G0,
    const float* __restrict__ Whh0,
    const float* __restrict__ Wih1, const float* __restrict__ Whh1,
    const float* __restrict__ bih1, const float* __restrict__ bhh1,
    const float* __restrict__ init_c,
    unsigned short* __restrict__ h0buf, unsigned short* __restrict__ h1buf,
    float* __restrict__ lstm_out,
    unsigned* __restrict__ bar)
{
    __shared__ float g0l[32 * 33];             // 4224 B
    __shared__ float g1l[32 * 33];             // 4224 B
    __shared__ float c0s[8 * 33];
    __shared__ float c1s[8 * 33];
    __shared__ float bias1[32];

    int tid = threadIdx.x;
    int p = blockIdx.x;                        // 0..63
    int lane = tid & 63, w = tid >> 6;
    int mt = w & 1, nt = w >> 1;
    int lr = nt * 16 + (lane & 15);            // local gate col 0..31
    int gr = (lr >> 3) * H_ + p * 8 + (lr & 7);// global gate row
    int kb = (lane >> 4) * 8;

    unsigned char* flags = (unsigned char*)bar + 64;

    // preload weight fragments into registers (192 regs)
    short8 B0[16], B1[32];
    #pragma unroll
    for (int ks = 0; ks < 16; ks++) {
        const float* s0 = Whh0 + (size_t)gr * H_ + ks * 32 + kb;
        const float* s1 = Wih1 + (size_t)gr * H_ + ks * 32 + kb;
        const float* s2 = Whh1 + (size_t)gr * H_ + ks * 32 + kb;
        float4 a = *(const float4*)(s0), b = *(const float4*)(s0 + 4);
        short8 t0; t0[0]=f2bf(a.x);t0[1]=f2bf(a.y);t0[2]=f2bf(a.z);t0[3]=f2bf(a.w);
                   t0[4]=f2bf(b.x);t0[5]=f2bf(b.y);t0[6]=f2bf(b.z);t0[7]=f2bf(b.w);
        B0[ks] = t0;
        a = *(const float4*)(s1); b = *(const float4*)(s1 + 4);
        short8 t1; t1[0]=f2bf(a.x);t1[1]=f2bf(a.y);t1[2]=f2bf(a.z);t1[3]=f2bf(a.w);
                   t1[4]=f2bf(b.x);t1[5]=f2bf(b.y);t1[6]=f2bf(b.z);t1[7]=f2bf(b.w);
        B1[ks] = t1;
        a = *(const float4*)(s2); b = *(const float4*)(s2 + 4);
        short8 t2; t2[0]=f2bf(a.x);t2[1]=f2bf(a.y);t2[2]=f2bf(a.z);t2[3]=f2bf(a.w);
                   t2[4]=f2bf(b.x);t2[5]=f2bf(b.y);t2[6]=f2bf(b.z);t2[7]=f2bf(b.w);
        B1[16 + ks] = t2;
    }
    if (tid < 32) {
        int g = (tid >> 3) * H_ + p * 8 + (tid & 7);
        bias1[tid] = bih1[g] + bhh1[g];
    }
    int uu = tid & 7, b8 = tid >> 3;
    c0s[uu * 33 + b8] = init_c[(size_t)b8 * H_ + p * 8 + uu];
    c1s[uu * 33 + b8] = init_c[(size_t)B_ * H_ + (size_t)b8 * H_ + p * 8 + uu];
    __syncthreads();

    // G0 pointer centered (+2H) so 4 gate loads fit signed 13-bit immediates
    const float* gptr = G0 + (size_t)b8 * S_ * G4H + p * 8 + uu + 2 * H_;
    // fragment-major store index for this thread's 8-unit group (used at uu==0)
    int sidx = ((b8 >> 4) * 8192) + ((p >> 2) * 512) + (((p & 3) * 16 + (b8 & 15)) * 8);

    for (int it = 0; it <= S_; it++) {
        // ---- prefetch G0[t] gate pre-activations (plain cached loads, pinned) ----
        float gpre0 = 0.f, gpre1 = 0.f, gpre2 = 0.f, gpre3 = 0.f;
        if (it < S_) {
            const float* gsrc = gptr + (size_t)it * G4H;
            PLD32(gpre0, gsrc, "-4096");
            PLD32(gpre1, gsrc, "-2048");
            PLD32(gpre2, gsrc, "0");
            PLD32(gpre3, gsrc, "2048");
        }
        // ---- wait for step it-1's h stores: all 64 flags >= it (one load/lane) ----
        if (it) {
            unsigned tgt = (unsigned)it;
            const unsigned char* fp = flags + lane;
            for (;;) {
                unsigned fvv;
                asm volatile("global_load_ubyte %0, %1, off sc0 sc1" : "=v"(fvv) : "v"(fp));
                asm volatile("s_waitcnt vmcnt(0)" : "+v"(fvv));
                if (__all((int)(fvv >= tgt))) break;
                __builtin_amdgcn_s_sleep(1);
            }
        }
        // ---- coalesced fragment loads: h0 state[it], h1 state[it-1] ----
        const unsigned short* b0p = h0buf + (it & 1) * 16384 + mt * 8192 + lane * 8;
        const unsigned short* b1p = h1buf + ((it + 1) & 1) * 16384 + mt * 8192 + lane * 8;
        short8 F0[16], F1[16];
        CLDPLANE(F0, b0p);
        CLDPLANE(F1, b1p);

        // single drain; ties make fragment/gate registers unusable until data lands
        asm volatile("s_waitcnt vmcnt(0)"
            : "+v"(F0[0]),"+v"(F0[1]),"+v"(F0[2]),"+v"(F0[3]),
              "+v"(F0[4]),"+v"(F0[5]),"+v"(F0[6]),"+v"(F0[7]),
              "+v"(F0[8]),"+v"(F0[9]),"+v"(F0[10]),"+v"(F0[11]),
              "+v"(F0[12]),"+v"(F0[13]),"+v"(F0[14]),"+v"(F0[15]),
              "+v"(F1[0]),"+v"(F1[1]),"+v"(F1[2]),"+v"(F1[3]),
              "+v"(F1[4]),"+v"(F1[5]),"+v"(F1[6]),"+v"(F1[7]),
              "+v"(F1[8]),"+v"(F1[9]),"+v"(F1[10]),"+v"(F1[11]),
              "+v"(F1[12]),"+v"(F1[13]),"+v"(F1[14]),"+v"(F1[15]),
              "+v"(gpre0),"+v"(gpre1),"+v"(gpre2),"+v"(gpre3));

        f32x4 acc0 = {0.f,0.f,0.f,0.f};
        f32x4 a1a  = {0.f,0.f,0.f,0.f};
        f32x4 a1b  = {0.f,0.f,0.f,0.f};
        #pragma unroll
        for (int ks = 0; ks < 16; ks++) {
            acc0 = __builtin_amdgcn_mfma_f32_16x16x32_bf16(F0[ks], B0[ks],      acc0, 0, 0, 0);
            a1a  = __builtin_amdgcn_mfma_f32_16x16x32_bf16(F0[ks], B1[ks],      a1a,  0, 0, 0);
            a1b  = __builtin_amdgcn_mfma_f32_16x16x32_bf16(F1[ks], B1[16 + ks], a1b,  0, 0, 0);
        }
        #pragma unroll
        for (int r = 0; r < 4; r++) {
            int row = mt * 16 + (lane >> 4) * 4 + r;
            g0l[row * 33 + lr] = acc0[r];
            g1l[row * 33 + lr] = a1a[r] + a1b[r];
        }
        __syncthreads();

        if (it < S_) {
            float iv = g0l[b8 * 33 + uu]       + gpre0;
            float fv = g0l[b8 * 33 + 8 + uu]   + gpre1;
            float gv = g0l[b8 * 33 + 16 + uu]  + gpre2;
            float ov = g0l[b8 * 33 + 24 + uu]  + gpre3;
            float c = c0s[uu * 33 + b8];
            c = sigf(fv) * c + sigf(iv) * tanhf(gv);
            c0s[uu * 33 + b8] = c;
            float h = sigf(ov) * tanhf(c);
            unsigned short hb = f2bf(h);
            float hn = __shfl_down(h, 1, 64);
            unsigned pk = (unsigned)hb | ((unsigned)f2bf(hn) << 16);
            unsigned q  = (unsigned)__shfl_down((int)pk, 2, 64);
            unsigned r0 = (unsigned)__shfl_down((int)pk, 4, 64);
            unsigned r1 = (unsigned)__shfl_down((int)q,  4, 64);
            if (!(tid & 7)) {   // one 16B coherent store per 8-unit group
                u32x4 val = {pk, q, r0, r1};
                unsigned short* dst = h0buf + ((it + 1) & 1) * 16384 + sidx;
                CST128(dst, val);
            }
        }
        if (it >= 1) {
            float iv = g1l[b8 * 33 + uu]       + bias1[uu];
            float fv = g1l[b8 * 33 + 8 + uu]   + bias1[8 + uu];
            float gv = g1l[b8 * 33 + 16 + uu]  + bias1[16 + uu];
            float ov = g1l[b8 * 33 + 24 + uu]  + bias1[24 + uu];
            float c = c1s[uu * 33 + b8];
            c = sigf(fv) * c + sigf(iv) * tanhf(gv);
            c1s[uu * 33 + b8] = c;
            float h = sigf(ov) * tanhf(c);
            unsigned short hb = f2bf(h);
            float hn = __shfl_down(h, 1, 64);
            unsigned pk = (unsigned)hb | ((unsigned)f2bf(hn) << 16);
            unsigned q  = (unsigned)__shfl_down((int)pk, 2, 64);
            unsigned r0 = (unsigned)__shfl_down((int)pk, 4, 64);
            unsigned r1 = (unsigned)__shfl_down((int)q,  4, 64);
            if (!(tid & 7)) {
                u32x4 val = {pk, q, r0, r1};
                unsigned short* dst = h1buf + (it & 1) * 16384 + sidx;
                CST128(dst, val);
            }
            lstm_out[(size_t)(b8 * S_ + (it - 1)) * H_ + p * 8 + uu] = h;
        }

        if (it < S_) {
            // drain own coherent stores, block-sync, publish flag; waves then
            // self-release via the 64-flag poll at the top of the next iteration
            asm volatile("s_waitcnt vmcnt(0)" ::: "memory");
            __syncthreads();
            if (tid == 0) {
                unsigned fv = (unsigned)(it + 1);
                const unsigned char* fp = flags + p;
                CSTB(fp, fv);
            }
        }
    }
}

// ---------------- gathered prediction + BCE ----------------
__global__ __launch_bounds__(256) void pred_kernel(
    const float* __restrict__ lstm_out, const float* __restrict__ cn,
    const float* __restrict__ Wp, const float* __restrict__ bp,
    const int* __restrict__ qt, const float* __restrict__ target,
    float* __restrict__ out, float* __restrict__ accum)
{
    int wv = (blockIdx.x * 256 + threadIdx.x) >> 6;   // one wave per row
    int lane = threadIdx.x & 63;
    if (wv >= NROW) return;
    int q = qt[wv];
    const float* wrow = Wp + (size_t)q * (H_ + NF_);
    const float* hrow = lstm_out + (size_t)wv * H_;
    float part = 0.f;
    #pragma unroll
    for (int i = 0; i < H_ / 64; i++) part += hrow[lane + i * 64] * wrow[lane + i * 64];
    if (lane < NF_) part += cn[(size_t)wv * NF_ + lane] * wrow[H_ + lane];
    #pragma unroll
    for (int off = 32; off; off >>= 1) part += __shfl_down(part, off, 64);
    if (lane == 0) {
        float x = part + bp[q];
        float t = target[wv];
        float mask = (q > 0) ? 1.f : 0.f;
        out[1 + wv] = mask / (1.f + __expf(-x));
        out[1 + NROW + wv] = t * mask;
        float bce = fmaxf(x, 0.f) - x * t + log1pf(__expf(-fabsf(x)));
        atomicAdd(&accum[0], bce * mask);
        atomicAdd(&accum[1], mask);
    }
}

__global__ void final_kernel(const float* __restrict__ accum, float* __restrict__ out)
{
    out[0] = accum[0] / accum[1];
}

extern "C" void kernel_launch(void* const* d_in, const int* in_sizes, int n_in,
                              void* d_out, int out_size, void* d_ws, size_t ws_size,
                              hipStream_t stream)
{
    (void)in_sizes; (void)n_in; (void)out_size; (void)ws_size;
    const int*   x_data = (const int*)  d_in[0];
    const int*   q_t    = (const int*)  d_in[1];
    const float* target = (const float*)d_in[2];
    const float* rep    = (const float*)d_in[3];
    const float* past   = (const float*)d_in[4];
    const float* seq    = (const float*)d_in[5];
    const float* embed  = (const float*)d_in[6];
    const float* Wih0   = (const float*)d_in[7];
    const float* Whh0   = (const float*)d_in[8];
    const float* bih0   = (const float*)d_in[9];
    const float* bhh0   = (const float*)d_in[10];
    const float* Wih1   = (const float*)d_in[11];
    const float* Whh1   = (const float*)d_in[12];
    const float* bih1   = (const float*)d_in[13];
    const float* bhh1   = (const float*)d_in[14];
    const float* Wp     = (const float*)d_in[15];
    const float* bp     = (const float*)d_in[16];
    const float* C      = (const float*)d_in[17];
    const float* init_h = (const float*)d_in[18];
    const float* init_c = (const float*)d_in[19];

    char* ws = (char*)d_ws;
    float*          G0    = (float*)         (ws + OFF_G0);
    float*          lstm  = (float*)         (ws + OFF_LSTM);
    float*          ct    = (float*)         (ws + OFF_CT);
    float*          cn    = (float*)         (ws + OFF_CN);
    unsigned short* h0buf = (unsigned short*)(ws + OFF_H0);
    unsigned short* h1buf = (unsigned short*)(ws + OFF_H1);
    unsigned*       sync  = (unsigned*)      (ws + OFF_SYNC);
    unsigned short* wb    = (unsigned short*)(ws + OFF_WB);
    float* out = (float*)d_out;

    prep_kernel<<<540, 256, 0, stream>>>(C, rep, past, seq, init_h, ct, cn, h0buf, h1buf, sync);
    prepw_kernel<<<(G4H * KP_ + 255) / 256, 256, 0, stream>>>(Wih0, wb);
    g0_kernel<<<6400, 256, 0, stream>>>(x_data, embed, wb, bih0, bhh0, ct, G0);
    scan_kernel<<<64, 256, 0, stream>>>(G0, Whh0, Wih1, Whh1, bih1, bhh1, init_c,
                                        h0buf, h1buf, lstm, sync);
    pred_kernel<<<NROW / 4, 256, 0, stream>>>(lstm, cn, Wp, bp, q_t, target, out,
                                              (float*)(sync + 1));
    final_kernel<<<1, 1, 0, stream>>>((const float*)(sync + 1), out);
}

// Round 3
// 1150.627 us; speedup vs baseline: 1.5029x; 1.3095x over previous
//
#include <hip/hip_runtime.h>
#include <hip/hip_bf16.h>

#define B_   32
#define S_   200
#define H_   512
#define ED_  256
#define NF_  19
#define NROW (B_*S_)      // 6400
#define G4H  (4*H_)       // 2048
#define KIN  (ED_+NF_)    // 275
#define KP_  288          // padded K for input GEMM
#define ALD  296          // A-tile LDS row stride (bf16)

typedef __attribute__((ext_vector_type(8))) short short8;
typedef __attribute__((ext_vector_type(4))) float f32x4;
typedef __attribute__((ext_vector_type(4))) unsigned int u32x4;

// ---------------- workspace layout (bytes) ----------------
#define OFF_G0   0ull
#define SZ_G0    ((size_t)NROW*G4H*4)            // 52428800
#define OFF_LSTM (OFF_G0 + SZ_G0)
#define SZ_LSTM  ((size_t)NROW*H_*4)             // 13107200
#define OFF_CT   (OFF_LSTM + SZ_LSTM)
#define SZ_CT    ((size_t)NROW*NF_*4)            // 486400
#define OFF_CN   (OFF_CT + SZ_CT)
#define OFF_H0   (OFF_CN + SZ_CT)
#define SZ_HB    ((size_t)2*B_*H_*2)             // 65536 (bf16 double buffer)
#define OFF_H1   (OFF_H0 + SZ_HB)
// sync area: u32[0..1] = pred accum; byte 256.. : flags[64], ONE PER 64B LINE
#define OFF_SYNC (OFF_H1 + SZ_HB)
#define OFF_WB   (OFF_SYNC + 8192)               // Wih0 pre-converted bf16 [2048][288]
#define SZ_WB    ((size_t)G4H*KP_*2)             // 1179648

__device__ __forceinline__ unsigned short f2bf(float f) {
    unsigned u = __float_as_uint(f);
    unsigned r = u + 0x7fffu + ((u >> 16) & 1u);
    return (unsigned short)(r >> 16);
}
__device__ __forceinline__ float sigf(float x) { return 1.0f / (1.0f + __expf(-x)); }

// coherent (agent-scope) 16B load, bypasses L1/L2, served at the MALL
#define CLD16(d, p, o) \
    asm volatile("global_load_dwordx4 %0, %1, off offset:" o " sc0 sc1" \
                 : "=v"(d) : "v"(p))
// one fragment plane (16 chunks x 1KB), fully coalesced: lane*16B + j*1024B
#define CLDPLANE(F, b) do { \
    const unsigned short* _pa = (b) + 2048; \
    const unsigned short* _pb = (b) + 6144; \
    CLD16(F[0],_pa,"-4096"); CLD16(F[1],_pa,"-3072"); CLD16(F[2],_pa,"-2048"); CLD16(F[3],_pa,"-1024"); \
    CLD16(F[4],_pa,"0");     CLD16(F[5],_pa,"1024");  CLD16(F[6],_pa,"2048");  CLD16(F[7],_pa,"3072");  \
    CLD16(F[8],_pb,"-4096"); CLD16(F[9],_pb,"-3072"); CLD16(F[10],_pb,"-2048");CLD16(F[11],_pb,"-1024");\
    CLD16(F[12],_pb,"0");    CLD16(F[13],_pb,"1024"); CLD16(F[14],_pb,"2048"); CLD16(F[15],_pb,"3072"); \
} while (0)
// coherent 16B store
#define CST128(a, v) \
    asm volatile("global_store_dwordx4 %0, %1, off sc0 sc1" :: "v"(a), "v"(v) : "memory")
// plain (cached) 4B load, issue point pinned by asm volatile ordering
#define PLD32(d, p, o) \
    asm volatile("global_load_dword %0, %1, off offset:" o : "=v"(d) : "v"(p))

// fragment-major bf16 index within one parity buffer (16384 elems):
// idx(b,u) = (b>>4)*8192 + (u>>5)*512 + (((u>>3)&3)*16 + (b&15))*8 + (u&7)

// ---------------- prep: c_t/c_next, h-buffer init (fragment-major), sync zero ----------------
__global__ __launch_bounds__(256) void prep_kernel(
    const float* __restrict__ C, const float* __restrict__ rep,
    const float* __restrict__ past, const float* __restrict__ seq,
    const float* __restrict__ init_h,
    float* __restrict__ ct, float* __restrict__ cn,
    unsigned short* __restrict__ h0buf, unsigned short* __restrict__ h1buf,
    unsigned* __restrict__ syncbuf)
{
    int idx = blockIdx.x * 256 + threadIdx.x;
    if (idx < NROW * NF_) {
        int m = idx % NF_; int row = idx / NF_;
        int b = row / S_, s = row % S_;
        float cc = C[idx];
        float v0, v1;
        if (m < 7)       { v0 = rep [(b*(S_+1)+s)*7 + m];      v1 = rep [(b*(S_+1)+s+1)*7 + m]; }
        else if (m < 13) { v0 = seq [(b*(S_+1)+s)*6 + (m-7)];  v1 = seq [(b*(S_+1)+s+1)*6 + (m-7)]; }
        else             { v0 = past[(b*(S_+1)+s)*6 + (m-13)]; v1 = past[(b*(S_+1)+s+1)*6 + (m-13)]; }
        ct[idx] = cc * v0;
        cn[idx] = cc * v1;
    }
    int j = idx - NROW * NF_;
    if (j >= 0 && j < B_ * H_) {
        int b = j >> 9, u = j & (H_ - 1);
        int fi = ((b >> 4) * 8192) + ((u >> 5) * 512)
               + ((((u >> 3) & 3) * 16 + (b & 15)) * 8) + (u & 7);
        h0buf[fi] = f2bf(init_h[j]);
        h1buf[fi] = f2bf(init_h[B_ * H_ + j]);
    }
    if (j >= B_ * H_ && j < B_ * H_ + 1100) syncbuf[j - B_ * H_] = 0u;
}

// ---------------- prep_w: Wih0 f32[2048][275] -> bf16[2048][288] (zero-pad) ----------------
__global__ __launch_bounds__(256) void prepw_kernel(
    const float* __restrict__ Wih0, unsigned short* __restrict__ wb)
{
    int idx = blockIdx.x * 256 + threadIdx.x;
    if (idx >= G4H * KP_) return;
    int k = idx % KP_; int r = idx / KP_;
    wb[idx] = (k < KIN) ? f2bf(Wih0[(size_t)r * KIN + k]) : (unsigned short)0;
}

// ---------------- G0 = [emb|c_t] @ Wih0^T + bih0 + bhh0  (bf16 MFMA) ----------------
__global__ __launch_bounds__(256) void g0_kernel(
    const int* __restrict__ x_data, const float* __restrict__ embed,
    const unsigned short* __restrict__ wb,
    const float* __restrict__ bih0, const float* __restrict__ bhh0,
    const float* __restrict__ ct, float* __restrict__ G0)
{
    __shared__ unsigned short A[32 * ALD];
    int tid = threadIdx.x;
    int bx = blockIdx.x;
    int mb = bx >> 5;          // 0..199  (row tile of 32)
    int nb = bx & 31;          // 0..31   (col tile of 64)
    int rbase = mb * 32;
    {   // stage A: 32 gathered rows of [emb(256)|c_t(19)|pad]
        int r = tid >> 3, c8 = tid & 7;
        int grow = rbase + r;
        const float* erow = embed + (size_t)x_data[grow] * ED_;
        #pragma unroll
        for (int jj = 0; jj < 8; jj++) {
            float4 v = *(const float4*)(erow + c8 * 32 + jj * 4);
            unsigned short* d = &A[r * ALD + c8 * 32 + jj * 4];
            d[0] = f2bf(v.x); d[1] = f2bf(v.y); d[2] = f2bf(v.z); d[3] = f2bf(v.w);
        }
        if (c8 == 0) {
            const float* crow = ct + (size_t)grow * NF_;
            for (int m = 0; m < NF_; m++) A[r * ALD + ED_ + m] = f2bf(crow[m]);
            for (int m = NF_; m < 32; m++) A[r * ALD + ED_ + m] = 0;
        }
    }
    __syncthreads();
    int lane = tid & 63, w = tid >> 6;
    int ncol = nb * 64 + w * 16 + (lane & 15);   // global gate row
    int kb = (lane >> 4) * 8;
    f32x4 acc0 = {0.f,0.f,0.f,0.f}, acc1 = {0.f,0.f,0.f,0.f};
    #pragma unroll
    for (int ks = 0; ks < 9; ks++) {
        int k0 = ks * 32 + kb;
        short8 bfr = *(const short8*)(wb + (size_t)ncol * KP_ + k0);
        short8 a0 = *(const short8*)&A[(lane & 15) * ALD + k0];
        short8 a1 = *(const short8*)&A[(16 + (lane & 15)) * ALD + k0];
        acc0 = __builtin_amdgcn_mfma_f32_16x16x32_bf16(a0, bfr, acc0, 0, 0, 0);
        acc1 = __builtin_amdgcn_mfma_f32_16x16x32_bf16(a1, bfr, acc1, 0, 0, 0);
    }
    float bias = bih0[ncol] + bhh0[ncol];
    #pragma unroll
    for (int r = 0; r < 4; r++) {
        int row0 = (lane >> 4) * 4 + r;
        G0[(size_t)(rbase + row0) * G4H + ncol]      = acc0[r] + bias;
        G0[(size_t)(rbase + 16 + row0) * G4H + ncol] = acc1[r] + bias;
    }
}

// ---------------- persistent 2-layer LSTM scan ----------------
// 64 blocks x 256 threads. Block p owns units [8p, 8p+8) of each layer.
// Weights stationary in VGPRs. h exchanged through global bf16 double buffers
// (fragment-major -> fully coalesced consumer loads, 1KB/instruction).
// Grid sync: ONE FLAG PER 64B LINE (u32, stride 16 u32) -- producer stores
// go to 64 distinct lines (parallel, no line serialization at the MALL);
// each polling wave reads all 64 flags with one load (lane -> line).
// lstm_out (plain store) is issued AFTER flag publication: off the drain path.
__global__ __launch_bounds__(256, 1) void scan_kernel(
    const float* __restrict__ G0,
    const float* __restrict__ Whh0,
    const float* __restrict__ Wih1, const float* __restrict__ Whh1,
    const float* __restrict__ bih1, const float* __restrict__ bhh1,
    const float* __restrict__ init_c,
    unsigned short* __restrict__ h0buf, unsigned short* __restrict__ h1buf,
    float* __restrict__ lstm_out,
    unsigned* __restrict__ bar)
{
    __shared__ float g0l[32 * 33];             // 4224 B
    __shared__ float g1l[32 * 33];             // 4224 B
    __shared__ float c0s[8 * 33];
    __shared__ float c1s[8 * 33];
    __shared__ float bias1[32];

    int tid = threadIdx.x;
    int p = blockIdx.x;                        // 0..63
    int lane = tid & 63, w = tid >> 6;
    int mt = w & 1, nt = w >> 1;
    int lr = nt * 16 + (lane & 15);            // local gate col 0..31
    int gr = (lr >> 3) * H_ + p * 8 + (lr & 7);// global gate row
    int kb = (lane >> 4) * 8;

    unsigned* flagw = bar + 64;                // byte 256: flags, 64B stride

    // preload weight fragments into registers (192 regs)
    short8 B0[16], B1[32];
    #pragma unroll
    for (int ks = 0; ks < 16; ks++) {
        const float* s0 = Whh0 + (size_t)gr * H_ + ks * 32 + kb;
        const float* s1 = Wih1 + (size_t)gr * H_ + ks * 32 + kb;
        const float* s2 = Whh1 + (size_t)gr * H_ + ks * 32 + kb;
        float4 a = *(const float4*)(s0), b = *(const float4*)(s0 + 4);
        short8 t0; t0[0]=f2bf(a.x);t0[1]=f2bf(a.y);t0[2]=f2bf(a.z);t0[3]=f2bf(a.w);
                   t0[4]=f2bf(b.x);t0[5]=f2bf(b.y);t0[6]=f2bf(b.z);t0[7]=f2bf(b.w);
        B0[ks] = t0;
        a = *(const float4*)(s1); b = *(const float4*)(s1 + 4);
        short8 t1; t1[0]=f2bf(a.x);t1[1]=f2bf(a.y);t1[2]=f2bf(a.z);t1[3]=f2bf(a.w);
                   t1[4]=f2bf(b.x);t1[5]=f2bf(b.y);t1[6]=f2bf(b.z);t1[7]=f2bf(b.w);
        B1[ks] = t1;
        a = *(const float4*)(s2); b = *(const float4*)(s2 + 4);
        short8 t2; t2[0]=f2bf(a.x);t2[1]=f2bf(a.y);t2[2]=f2bf(a.z);t2[3]=f2bf(a.w);
                   t2[4]=f2bf(b.x);t2[5]=f2bf(b.y);t2[6]=f2bf(b.z);t2[7]=f2bf(b.w);
        B1[16 + ks] = t2;
    }
    if (tid < 32) {
        int g = (tid >> 3) * H_ + p * 8 + (tid & 7);
        bias1[tid] = bih1[g] + bhh1[g];
    }
    int uu = tid & 7, b8 = tid >> 3;
    c0s[uu * 33 + b8] = init_c[(size_t)b8 * H_ + p * 8 + uu];
    c1s[uu * 33 + b8] = init_c[(size_t)B_ * H_ + (size_t)b8 * H_ + p * 8 + uu];
    __syncthreads();

    // G0 pointer centered (+2H) so 4 gate loads fit signed 13-bit immediates
    const float* gptr = G0 + (size_t)b8 * S_ * G4H + p * 8 + uu + 2 * H_;
    // fragment-major store index for this thread's 8-unit group (used at tid&7==0)
    int sidx = ((b8 >> 4) * 8192) + ((p >> 2) * 512) + (((p & 3) * 16 + (b8 & 15)) * 8);

    for (int it = 0; it <= S_; it++) {
        // ---- prefetch G0[t] gate pre-activations (plain cached loads, pinned) ----
        float gpre0 = 0.f, gpre1 = 0.f, gpre2 = 0.f, gpre3 = 0.f;
        if (it < S_) {
            const float* gsrc = gptr + (size_t)it * G4H;
            PLD32(gpre0, gsrc, "-4096");
            PLD32(gpre1, gsrc, "-2048");
            PLD32(gpre2, gsrc, "0");
            PLD32(gpre3, gsrc, "2048");
        }
        // ---- wait for step it-1's h stores: all 64 flags >= it (lane -> own line) ----
        if (it) {
            unsigned tgt = (unsigned)it;
            const unsigned* fp = flagw + lane * 16;
            for (;;) {
                unsigned fvv;
                asm volatile("global_load_dword %0, %1, off sc0 sc1" : "=v"(fvv) : "v"(fp));
                asm volatile("s_waitcnt vmcnt(0)" : "+v"(fvv));
                if (__all((int)(fvv >= tgt))) break;
                __builtin_amdgcn_s_sleep(1);
            }
        }
        // ---- coalesced fragment loads: h0 state[it], h1 state[it-1] ----
        const unsigned short* b0p = h0buf + (it & 1) * 16384 + mt * 8192 + lane * 8;
        const unsigned short* b1p = h1buf + ((it + 1) & 1) * 16384 + mt * 8192 + lane * 8;
        short8 F0[16], F1[16];
        CLDPLANE(F0, b0p);
        CLDPLANE(F1, b1p);

        // single drain; ties make fragment/gate registers unusable until data lands
        asm volatile("s_waitcnt vmcnt(0)"
            : "+v"(F0[0]),"+v"(F0[1]),"+v"(F0[2]),"+v"(F0[3]),
              "+v"(F0[4]),"+v"(F0[5]),"+v"(F0[6]),"+v"(F0[7]),
              "+v"(F0[8]),"+v"(F0[9]),"+v"(F0[10]),"+v"(F0[11]),
              "+v"(F0[12]),"+v"(F0[13]),"+v"(F0[14]),"+v"(F0[15]),
              "+v"(F1[0]),"+v"(F1[1]),"+v"(F1[2]),"+v"(F1[3]),
              "+v"(F1[4]),"+v"(F1[5]),"+v"(F1[6]),"+v"(F1[7]),
              "+v"(F1[8]),"+v"(F1[9]),"+v"(F1[10]),"+v"(F1[11]),
              "+v"(F1[12]),"+v"(F1[13]),"+v"(F1[14]),"+v"(F1[15]),
              "+v"(gpre0),"+v"(gpre1),"+v"(gpre2),"+v"(gpre3));

        f32x4 acc0 = {0.f,0.f,0.f,0.f};
        f32x4 a1a  = {0.f,0.f,0.f,0.f};
        f32x4 a1b  = {0.f,0.f,0.f,0.f};
        #pragma unroll
        for (int ks = 0; ks < 16; ks++) {
            acc0 = __builtin_amdgcn_mfma_f32_16x16x32_bf16(F0[ks], B0[ks],      acc0, 0, 0, 0);
            a1a  = __builtin_amdgcn_mfma_f32_16x16x32_bf16(F0[ks], B1[ks],      a1a,  0, 0, 0);
            a1b  = __builtin_amdgcn_mfma_f32_16x16x32_bf16(F1[ks], B1[16 + ks], a1b,  0, 0, 0);
        }
        #pragma unroll
        for (int r = 0; r < 4; r++) {
            int row = mt * 16 + (lane >> 4) * 4 + r;
            g0l[row * 33 + lr] = acc0[r];
            g1l[row * 33 + lr] = a1a[r] + a1b[r];
        }
        __syncthreads();

        if (it < S_) {
            float iv = g0l[b8 * 33 + uu]       + gpre0;
            float fv = g0l[b8 * 33 + 8 + uu]   + gpre1;
            float gv = g0l[b8 * 33 + 16 + uu]  + gpre2;
            float ov = g0l[b8 * 33 + 24 + uu]  + gpre3;
            float c = c0s[uu * 33 + b8];
            c = sigf(fv) * c + sigf(iv) * tanhf(gv);
            c0s[uu * 33 + b8] = c;
            float h = sigf(ov) * tanhf(c);
            unsigned short hb = f2bf(h);
            float hn = __shfl_down(h, 1, 64);
            unsigned pk = (unsigned)hb | ((unsigned)f2bf(hn) << 16);
            unsigned q  = (unsigned)__shfl_down((int)pk, 2, 64);
            unsigned r0 = (unsigned)__shfl_down((int)pk, 4, 64);
            unsigned r1 = (unsigned)__shfl_down((int)q,  4, 64);
            if (!(tid & 7)) {   // one 16B coherent store per 8-unit group
                u32x4 val = {pk, q, r0, r1};
                unsigned short* dst = h0buf + ((it + 1) & 1) * 16384 + sidx;
                CST128(dst, val);
            }
        }
        float h1out = 0.f;
        if (it >= 1) {
            float iv = g1l[b8 * 33 + uu]       + bias1[uu];
            float fv = g1l[b8 * 33 + 8 + uu]   + bias1[8 + uu];
            float gv = g1l[b8 * 33 + 16 + uu]  + bias1[16 + uu];
            float ov = g1l[b8 * 33 + 24 + uu]  + bias1[24 + uu];
            float c = c1s[uu * 33 + b8];
            c = sigf(fv) * c + sigf(iv) * tanhf(gv);
            c1s[uu * 33 + b8] = c;
            float h = sigf(ov) * tanhf(c);
            h1out = h;
            unsigned short hb = f2bf(h);
            float hn = __shfl_down(h, 1, 64);
            unsigned pk = (unsigned)hb | ((unsigned)f2bf(hn) << 16);
            unsigned q  = (unsigned)__shfl_down((int)pk, 2, 64);
            unsigned r0 = (unsigned)__shfl_down((int)pk, 4, 64);
            unsigned r1 = (unsigned)__shfl_down((int)q,  4, 64);
            if (!(tid & 7)) {
                u32x4 val = {pk, q, r0, r1};
                unsigned short* dst = h1buf + (it & 1) * 16384 + sidx;
                CST128(dst, val);
            }
        }

        if (it < S_) {
            // drain own coherent stores, block-sync, publish own flag line
            asm volatile("s_waitcnt vmcnt(0)" ::: "memory");
            __syncthreads();
            if (tid == 0) {
                unsigned fv = (unsigned)(it + 1);
                unsigned* fp = flagw + p * 16;
                asm volatile("global_store_dword %0, %1, off sc0 sc1"
                             :: "v"(fp), "v"(fv) : "memory");
            }
        }
        // plain store AFTER flag: its HBM ack is off the barrier's drain path
        if (it >= 1) {
            lstm_out[(size_t)(b8 * S_ + (it - 1)) * H_ + p * 8 + uu] = h1out;
        }
    }
}

// ---------------- gathered prediction + BCE ----------------
__global__ __launch_bounds__(256) void pred_kernel(
    const float* __restrict__ lstm_out, const float* __restrict__ cn,
    const float* __restrict__ Wp, const float* __restrict__ bp,
    const int* __restrict__ qt, const float* __restrict__ target,
    float* __restrict__ out, float* __restrict__ accum)
{
    int wv = (blockIdx.x * 256 + threadIdx.x) >> 6;   // one wave per row
    int lane = threadIdx.x & 63;
    if (wv >= NROW) return;
    int q = qt[wv];
    const float* wrow = Wp + (size_t)q * (H_ + NF_);
    const float* hrow = lstm_out + (size_t)wv * H_;
    float part = 0.f;
    #pragma unroll
    for (int i = 0; i < H_ / 64; i++) part += hrow[lane + i * 64] * wrow[lane + i * 64];
    if (lane < NF_) part += cn[(size_t)wv * NF_ + lane] * wrow[H_ + lane];
    #pragma unroll
    for (int off = 32; off; off >>= 1) part += __shfl_down(part, off, 64);
    if (lane == 0) {
        float x = part + bp[q];
        float t = target[wv];
        float mask = (q > 0) ? 1.f : 0.f;
        out[1 + wv] = mask / (1.f + __expf(-x));
        out[1 + NROW + wv] = t * mask;
        float bce = fmaxf(x, 0.f) - x * t + log1pf(__expf(-fabsf(x)));
        atomicAdd(&accum[0], bce * mask);
        atomicAdd(&accum[1], mask);
    }
}

__global__ void final_kernel(const float* __restrict__ accum, float* __restrict__ out)
{
    out[0] = accum[0] / accum[1];
}

extern "C" void kernel_launch(void* const* d_in, const int* in_sizes, int n_in,
                              void* d_out, int out_size, void* d_ws, size_t ws_size,
                              hipStream_t stream)
{
    (void)in_sizes; (void)n_in; (void)out_size; (void)ws_size;
    const int*   x_data = (const int*)  d_in[0];
    const int*   q_t    = (const int*)  d_in[1];
    const float* target = (const float*)d_in[2];
    const float* rep    = (const float*)d_in[3];
    const float* past   = (const float*)d_in[4];
    const float* seq    = (const float*)d_in[5];
    const float* embed  = (const float*)d_in[6];
    const float* Wih0   = (const float*)d_in[7];
    const float* Whh0   = (const float*)d_in[8];
    const float* bih0   = (const float*)d_in[9];
    const float* bhh0   = (const float*)d_in[10];
    const float* Wih1   = (const float*)d_in[11];
    const float* Whh1   = (const float*)d_in[12];
    const float* bih1   = (const float*)d_in[13];
    const float* bhh1   = (const float*)d_in[14];
    const float* Wp     = (const float*)d_in[15];
    const float* bp     = (const float*)d_in[16];
    const float* C      = (const float*)d_in[17];
    const float* init_h = (const float*)d_in[18];
    const float* init_c = (const float*)d_in[19];

    char* ws = (char*)d_ws;
    float*          G0    = (float*)         (ws + OFF_G0);
    float*          lstm  = (float*)         (ws + OFF_LSTM);
    float*          ct    = (float*)         (ws + OFF_CT);
    float*          cn    = (float*)         (ws + OFF_CN);
    unsigned short* h0buf = (unsigned short*)(ws + OFF_H0);
    unsigned short* h1buf = (unsigned short*)(ws + OFF_H1);
    unsigned*       sync  = (unsigned*)      (ws + OFF_SYNC);
    unsigned short* wb    = (unsigned short*)(ws + OFF_WB);
    float* out = (float*)d_out;

    prep_kernel<<<544, 256, 0, stream>>>(C, rep, past, seq, init_h, ct, cn, h0buf, h1buf, sync);
    prepw_kernel<<<(G4H * KP_ + 255) / 256, 256, 0, stream>>>(Wih0, wb);
    g0_kernel<<<6400, 256, 0, stream>>>(x_data, embed, wb, bih0, bhh0, ct, G0);
    scan_kernel<<<64, 256, 0, stream>>>(G0, Whh0, Wih1, Whh1, bih1, bhh1, init_c,
                                        h0buf, h1buf, lstm, sync);
    pred_kernel<<<NROW / 4, 256, 0, stream>>>(lstm, cn, Wp, bp, q_t, target, out,
                                              (float*)sync);
    final_kernel<<<1, 1, 0, stream>>>((const float*)sync, out);
}